// Round 1
// baseline (68.823 us; speedup 1.0000x reference)
//
#include <hip/hip_runtime.h>
#include <math.h>

#define IMG      100
#define NPS      50          // patches per side
#define NPATCH   2500        // patches per image
#define NIMG     64
#define CHUNK    256         // patches per block
#define NCHUNK   10          // ceil(2500/256)

// ---- complex helpers on float2 ----
// RX(theta): [[c, -i s],[-i s, c]]
// RY(theta): [[c, -s],[s, c]]
// RZ(theta): diag(c - i s, c + i s)     (c=cos(theta/2), s=sin(theta/2))
// wire w in {0..3}, bit mask = 8>>w (wire0 = MSB)

__global__ __launch_bounds__(256) void quanv_dot_kernel(
    const float* __restrict__ x,     // [64,100,100]
    const float* __restrict__ W,     // [2,10000]
    const float* __restrict__ qp,    // [6]
    float* __restrict__ acc)         // [64,2] zero-initialized
{
    const int b     = blockIdx.x / NCHUNK;
    const int chunk = blockIdx.x % NCHUNK;
    const int p     = chunk * CHUNK + threadIdx.x;

    float t0 = 0.0f, t1 = 0.0f;   // partial dot for logits 0/1

    if (p < NPATCH) {
        // ---- gate params (broadcast loads) ----
        float gc[6], gs[6];
        #pragma unroll
        for (int k = 0; k < 6; ++k) {
            __sincosf(0.5f * qp[k], &gs[k], &gc[k]);
        }

        // ---- patch angles ----
        const int pi = p / NPS;           // patch row
        const int pj = p - pi * NPS;      // patch col
        const float* xb = x + b * (IMG * IMG) + (2 * pi) * IMG + 2 * pj;
        float ang0 = xb[0];
        float ang1 = xb[1];
        float ang2 = xb[IMG];
        float ang3 = xb[IMG + 1];

        float ca[4], sa[4];
        __sincosf(0.5f * ang0, &sa[0], &ca[0]);
        __sincosf(0.5f * ang1, &sa[1], &ca[1]);
        __sincosf(0.5f * ang2, &sa[2], &ca[2]);
        __sincosf(0.5f * ang3, &sa[3], &ca[3]);

        // ---- initial product state (real) ----
        float2 psi[16];
        #pragma unroll
        for (int i = 0; i < 16; ++i) {
            float v = ((i & 8) ? sa[0] : ca[0]) *
                      ((i & 4) ? sa[1] : ca[1]) *
                      ((i & 2) ? sa[2] : ca[2]) *
                      ((i & 1) ? sa[3] : ca[3]);
            psi[i] = make_float2(v, 0.0f);
        }

        // ---- gate sequence ----
        // RX(q0) wire0; RY(q1) wire1; RZ(q2) wire2; CNOT(0,1);
        // RX(q3) wire3; CNOT(2,3); RY(q4) wire0; RZ(q5) wire1

        #define APPLY_RX(m, c, s)                                              \
            _Pragma("unroll")                                                  \
            for (int i = 0; i < 16; ++i) if (!(i & (m))) {                     \
                int j = i | (m);                                               \
                float2 p0 = psi[i], p1 = psi[j];                               \
                psi[i] = make_float2((c)*p0.x + (s)*p1.y,                      \
                                     (c)*p0.y - (s)*p1.x);                     \
                psi[j] = make_float2((s)*p0.y + (c)*p1.x,                      \
                                    -(s)*p0.x + (c)*p1.y);                     \
            }

        #define APPLY_RY(m, c, s)                                              \
            _Pragma("unroll")                                                  \
            for (int i = 0; i < 16; ++i) if (!(i & (m))) {                     \
                int j = i | (m);                                               \
                float2 p0 = psi[i], p1 = psi[j];                               \
                psi[i] = make_float2((c)*p0.x - (s)*p1.x,                      \
                                     (c)*p0.y - (s)*p1.y);                     \
                psi[j] = make_float2((s)*p0.x + (c)*p1.x,                      \
                                     (s)*p0.y + (c)*p1.y);                     \
            }

        #define APPLY_RZ(m, c, s)                                              \
            _Pragma("unroll")                                                  \
            for (int i = 0; i < 16; ++i) {                                     \
                float2 pp = psi[i];                                            \
                if (i & (m)) {                                                 \
                    psi[i] = make_float2((c)*pp.x - (s)*pp.y,                  \
                                         (c)*pp.y + (s)*pp.x);                 \
                } else {                                                       \
                    psi[i] = make_float2((c)*pp.x + (s)*pp.y,                  \
                                         (c)*pp.y - (s)*pp.x);                 \
                }                                                              \
            }

        #define APPLY_CNOT(mc, mt)                                             \
            _Pragma("unroll")                                                  \
            for (int i = 0; i < 16; ++i) if ((i & (mc)) && !(i & (mt))) {      \
                int j = i | (mt);                                              \
                float2 tmp = psi[i]; psi[i] = psi[j]; psi[j] = tmp;            \
            }

        APPLY_RX(8, gc[0], gs[0]);     // RX(q0) wire0
        APPLY_RY(4, gc[1], gs[1]);     // RY(q1) wire1
        APPLY_RZ(2, gc[2], gs[2]);     // RZ(q2) wire2
        APPLY_CNOT(8, 4);              // CNOT(0,1)
        APPLY_RX(1, gc[3], gs[3]);     // RX(q3) wire3
        APPLY_CNOT(2, 1);              // CNOT(2,3)
        APPLY_RY(8, gc[4], gs[4]);     // RY(q4) wire0
        APPLY_RZ(4, gc[5], gs[5]);     // RZ(q5) wire1

        // ---- PauliZ expvals ----
        float e0 = 0.f, e1 = 0.f, e2 = 0.f, e3 = 0.f;
        #pragma unroll
        for (int i = 0; i < 16; ++i) {
            float pr = psi[i].x * psi[i].x + psi[i].y * psi[i].y;
            e0 += (i & 8) ? -pr : pr;
            e1 += (i & 4) ? -pr : pr;
            e2 += (i & 2) ? -pr : pr;
            e3 += (i & 1) ? -pr : pr;
        }

        // ---- dot with W rows (coalesced float4) ----
        const float4 w0 = reinterpret_cast<const float4*>(W)[p];
        const float4 w1 = reinterpret_cast<const float4*>(W)[NPATCH + p];
        t0 = e0 * w0.x + e1 * w0.y + e2 * w0.z + e3 * w0.w;
        t1 = e0 * w1.x + e1 * w1.y + e2 * w1.z + e3 * w1.w;
    }

    // ---- block reduction ----
    #pragma unroll
    for (int off = 32; off > 0; off >>= 1) {
        t0 += __shfl_down(t0, off);
        t1 += __shfl_down(t1, off);
    }
    __shared__ float red0[4], red1[4];
    const int lane = threadIdx.x & 63;
    const int wv   = threadIdx.x >> 6;
    if (lane == 0) { red0[wv] = t0; red1[wv] = t1; }
    __syncthreads();
    if (threadIdx.x == 0) {
        float a0 = red0[0] + red0[1] + red0[2] + red0[3];
        float a1 = red1[0] + red1[1] + red1[2] + red1[3];
        atomicAdd(&acc[b * 2 + 0], a0);
        atomicAdd(&acc[b * 2 + 1], a1);
    }
}

__global__ __launch_bounds__(64) void logsoftmax_kernel(
    const float* __restrict__ acc,   // [64,2]
    const float* __restrict__ bias,  // [2]
    float* __restrict__ out)         // [64,2]
{
    const int b = threadIdx.x;
    if (b < NIMG) {
        float l0 = acc[2 * b + 0] + bias[0];
        float l1 = acc[2 * b + 1] + bias[1];
        float m  = fmaxf(l0, l1);
        float lse = m + logf(__expf(l0 - m) + __expf(l1 - m));
        out[2 * b + 0] = l0 - lse;
        out[2 * b + 1] = l1 - lse;
    }
}

extern "C" void kernel_launch(void* const* d_in, const int* in_sizes, int n_in,
                              void* d_out, int out_size, void* d_ws, size_t ws_size,
                              hipStream_t stream) {
    const float* x    = (const float*)d_in[0];   // [64,100,100]
    const float* W    = (const float*)d_in[1];   // [2,10000]
    const float* bias = (const float*)d_in[2];   // [2]
    const float* qp   = (const float*)d_in[3];   // [6]
    float* out = (float*)d_out;                  // [64,2] fp32
    float* acc = (float*)d_ws;                   // [64,2] accumulator

    hipMemsetAsync(acc, 0, NIMG * 2 * sizeof(float), stream);
    quanv_dot_kernel<<<NIMG * NCHUNK, CHUNK, 0, stream>>>(x, W, qp, acc);
    logsoftmax_kernel<<<1, 64, 0, stream>>>(acc, bias, out);
}

// Round 2
// 66.098 us; speedup vs baseline: 1.0412x; 1.0412x over previous
//
#include <hip/hip_runtime.h>
#include <math.h>

#define IMG      100
#define NPS      50          // patches per side
#define NPATCH   2500        // patches per image
#define NIMG     64
#define BLK      1024        // threads per block (16 waves, 4/SIMD)

// One block per image. Each thread grid-strides over patches, simulating the
// 4-qubit circuit in registers and accumulating partial dots with W rows.
// Block-reduce -> thread 0 does bias + log_softmax -> writes 2 floats.
//
// Gate conventions (verified R1, absmax 0.0):
// RX(t): [[c, -i s],[-i s, c]]   RY(t): [[c, -s],[s, c]]
// RZ(t): diag(c - i s, c + i s)  with c=cos(t/2), s=sin(t/2)
// wire w in {0..3}, bit mask = 8>>w (wire0 = MSB)

__global__ __launch_bounds__(BLK) void quanv_fused_kernel(
    const float* __restrict__ x,     // [64,100,100]
    const float* __restrict__ W,     // [2,10000]
    const float* __restrict__ bias,  // [2]
    const float* __restrict__ qp,    // [6]
    float* __restrict__ out)         // [64,2]
{
    const int b = blockIdx.x;

    // ---- gate params (broadcast loads, computed once per thread) ----
    float gc[6], gs[6];
    #pragma unroll
    for (int k = 0; k < 6; ++k) {
        __sincosf(0.5f * qp[k], &gs[k], &gc[k]);
    }

    float t0 = 0.0f, t1 = 0.0f;   // partial dot for logits 0/1

    for (int p = threadIdx.x; p < NPATCH; p += BLK) {
        // ---- patch angles ----
        const int pi = p / NPS;           // patch row
        const int pj = p - pi * NPS;      // patch col
        const float* xb = x + b * (IMG * IMG) + (2 * pi) * IMG + 2 * pj;
        float ang0 = xb[0];
        float ang1 = xb[1];
        float ang2 = xb[IMG];
        float ang3 = xb[IMG + 1];

        float ca[4], sa[4];
        __sincosf(0.5f * ang0, &sa[0], &ca[0]);
        __sincosf(0.5f * ang1, &sa[1], &ca[1]);
        __sincosf(0.5f * ang2, &sa[2], &ca[2]);
        __sincosf(0.5f * ang3, &sa[3], &ca[3]);

        // ---- initial product state (real) ----
        float2 psi[16];
        #pragma unroll
        for (int i = 0; i < 16; ++i) {
            float v = ((i & 8) ? sa[0] : ca[0]) *
                      ((i & 4) ? sa[1] : ca[1]) *
                      ((i & 2) ? sa[2] : ca[2]) *
                      ((i & 1) ? sa[3] : ca[3]);
            psi[i] = make_float2(v, 0.0f);
        }

        // ---- gate sequence (identical to verified R1) ----
        #define APPLY_RX(m, c, s)                                              \
            _Pragma("unroll")                                                  \
            for (int i = 0; i < 16; ++i) if (!(i & (m))) {                     \
                int j = i | (m);                                               \
                float2 p0 = psi[i], p1 = psi[j];                               \
                psi[i] = make_float2((c)*p0.x + (s)*p1.y,                      \
                                     (c)*p0.y - (s)*p1.x);                     \
                psi[j] = make_float2((s)*p0.y + (c)*p1.x,                      \
                                    -(s)*p0.x + (c)*p1.y);                     \
            }

        #define APPLY_RY(m, c, s)                                              \
            _Pragma("unroll")                                                  \
            for (int i = 0; i < 16; ++i) if (!(i & (m))) {                     \
                int j = i | (m);                                               \
                float2 p0 = psi[i], p1 = psi[j];                               \
                psi[i] = make_float2((c)*p0.x - (s)*p1.x,                      \
                                     (c)*p0.y - (s)*p1.y);                     \
                psi[j] = make_float2((s)*p0.x + (c)*p1.x,                      \
                                     (s)*p0.y + (c)*p1.y);                     \
            }

        #define APPLY_RZ(m, c, s)                                              \
            _Pragma("unroll")                                                  \
            for (int i = 0; i < 16; ++i) {                                     \
                float2 pp = psi[i];                                            \
                if (i & (m)) {                                                 \
                    psi[i] = make_float2((c)*pp.x - (s)*pp.y,                  \
                                         (c)*pp.y + (s)*pp.x);                 \
                } else {                                                       \
                    psi[i] = make_float2((c)*pp.x + (s)*pp.y,                  \
                                         (c)*pp.y - (s)*pp.x);                 \
                }                                                              \
            }

        #define APPLY_CNOT(mc, mt)                                             \
            _Pragma("unroll")                                                  \
            for (int i = 0; i < 16; ++i) if ((i & (mc)) && !(i & (mt))) {      \
                int j = i | (mt);                                              \
                float2 tmp = psi[i]; psi[i] = psi[j]; psi[j] = tmp;            \
            }

        APPLY_RX(8, gc[0], gs[0]);     // RX(q0) wire0
        APPLY_RY(4, gc[1], gs[1]);     // RY(q1) wire1
        APPLY_RZ(2, gc[2], gs[2]);     // RZ(q2) wire2
        APPLY_CNOT(8, 4);              // CNOT(0,1)
        APPLY_RX(1, gc[3], gs[3]);     // RX(q3) wire3
        APPLY_CNOT(2, 1);              // CNOT(2,3)
        APPLY_RY(8, gc[4], gs[4]);     // RY(q4) wire0
        APPLY_RZ(4, gc[5], gs[5]);     // RZ(q5) wire1

        // ---- PauliZ expvals ----
        float e0 = 0.f, e1 = 0.f, e2 = 0.f, e3 = 0.f;
        #pragma unroll
        for (int i = 0; i < 16; ++i) {
            float pr = psi[i].x * psi[i].x + psi[i].y * psi[i].y;
            e0 += (i & 8) ? -pr : pr;
            e1 += (i & 4) ? -pr : pr;
            e2 += (i & 2) ? -pr : pr;
            e3 += (i & 1) ? -pr : pr;
        }

        // ---- dot with W rows (coalesced float4) ----
        const float4 w0 = reinterpret_cast<const float4*>(W)[p];
        const float4 w1 = reinterpret_cast<const float4*>(W)[NPATCH + p];
        t0 += e0 * w0.x + e1 * w0.y + e2 * w0.z + e3 * w0.w;
        t1 += e0 * w1.x + e1 * w1.y + e2 * w1.z + e3 * w1.w;
    }

    // ---- block reduction: wave shuffle, then LDS across 16 waves ----
    #pragma unroll
    for (int off = 32; off > 0; off >>= 1) {
        t0 += __shfl_down(t0, off);
        t1 += __shfl_down(t1, off);
    }
    __shared__ float red0[BLK / 64], red1[BLK / 64];
    const int lane = threadIdx.x & 63;
    const int wv   = threadIdx.x >> 6;
    if (lane == 0) { red0[wv] = t0; red1[wv] = t1; }
    __syncthreads();
    if (threadIdx.x == 0) {
        float l0 = 0.f, l1 = 0.f;
        #pragma unroll
        for (int w = 0; w < BLK / 64; ++w) { l0 += red0[w]; l1 += red1[w]; }
        l0 += bias[0];
        l1 += bias[1];
        float m   = fmaxf(l0, l1);
        float lse = m + logf(__expf(l0 - m) + __expf(l1 - m));
        out[b * 2 + 0] = l0 - lse;
        out[b * 2 + 1] = l1 - lse;
    }
}

extern "C" void kernel_launch(void* const* d_in, const int* in_sizes, int n_in,
                              void* d_out, int out_size, void* d_ws, size_t ws_size,
                              hipStream_t stream) {
    const float* x    = (const float*)d_in[0];   // [64,100,100]
    const float* W    = (const float*)d_in[1];   // [2,10000]
    const float* bias = (const float*)d_in[2];   // [2]
    const float* qp   = (const float*)d_in[3];   // [6]
    float* out = (float*)d_out;                  // [64,2] fp32

    quanv_fused_kernel<<<NIMG, BLK, 0, stream>>>(x, W, bias, qp, out);
}

// Round 4
// 60.967 us; speedup vs baseline: 1.1288x; 1.0842x over previous
//
#include <hip/hip_runtime.h>
#include <math.h>

#define IMG      100
#define NPS      50          // patches per side
#define NPATCH   2500        // patches per image
#define NIMG     64
#define BLK      1024        // threads per block (16 waves, 4/SIMD)

// One block per image; one dispatch total.
//
// Algebraic collapse of the 4-qubit circuit. Heisenberg evolution of Z_w
// backwards through RX0(q0) RY1(q1) RZ2(q2) CNOT01 RX3(q3) CNOT23 RY0(q4)
// RZ1(q5), with real per-qubit initial states RY(x_k)|0> so <Y>=0,
// <X_k>=sin x_k, <Z_k>=cos x_k:
//
//   Z0 -> cos q4 Z0 - sin q4 X0                         (RY0(q4))
//      -> cos q4 Z0 - sin q4 X0 X1                      (CNOT01: Xc -> Xc Xt)
//      -> cos q4 Z0 - sin q4 X0 (cos q1 X1 + sin q1 Z1) (RY1(q1))
//      -> cos q4 (cos q0 Z0 + sin q0 Y0) - ...          (RX0(q0))  [R3 BUG:
//                                       missing cos q0 on the Z0 term]
//   e0 = cos q0 cos q4 * cos x0 - sin q4 cos q1 * sin x0 sin x1
//                                - sin q4 sin q1 * sin x0 cos x1
//   e1 = cos q0 * cos x0 * (cos q1 cos x1 - sin q1 sin x1)
//   e2 = cos x2
//   e3 = cos q3 * cos x2 cos x3
// q2, q5 drop out entirely (RZ commutes with every Z it could reach).

__global__ __launch_bounds__(BLK) void quanv_fused_kernel(
    const float* __restrict__ x,     // [64,100,100]
    const float* __restrict__ W,     // [2,10000]
    const float* __restrict__ bias,  // [2]
    const float* __restrict__ qp,    // [6]
    float* __restrict__ out)         // [64,2]
{
    const int b = blockIdx.x;

    // ---- circuit coefficients from q_params (broadcast loads) ----
    const float C0 = __cosf(qp[0]);
    float S1, C1;  __sincosf(qp[1], &S1, &C1);
    const float C3 = __cosf(qp[3]);
    float S4, C4;  __sincosf(qp[4], &S4, &C4);

    const float k_a = C0 * C4;      // <- corrected (was C4 in R3)
    const float k_b = S4 * C1;
    const float k_c = S4 * S1;
    const float k_d = C0 * C1;
    const float k_e = C0 * S1;
    const float k_f = C3;

    float t0 = 0.0f, t1 = 0.0f;   // partial dot for logits 0/1

    const float* xb = x + b * (IMG * IMG);

    for (int p = threadIdx.x; p < NPATCH; p += BLK) {
        const int pi = p / NPS;           // patch row
        const int pj = p - pi * NPS;      // patch col

        // two float2 loads (row starts are even -> 8B aligned)
        const float2 r0 = *reinterpret_cast<const float2*>(xb + (2 * pi) * IMG + 2 * pj);
        const float2 r1 = *reinterpret_cast<const float2*>(xb + (2 * pi + 1) * IMG + 2 * pj);
        const float x0 = r0.x, x1 = r0.y, x2 = r1.x, x3 = r1.y;

        float sx0, cz0, sx1, cz1;
        __sincosf(x0, &sx0, &cz0);
        __sincosf(x1, &sx1, &cz1);
        const float cz2 = __cosf(x2);
        const float cz3 = __cosf(x3);

        const float e0 = k_a * cz0 - k_b * sx0 * sx1 - k_c * sx0 * cz1;
        const float e1 = k_d * cz0 * cz1 - k_e * cz0 * sx1;
        const float e2 = cz2;
        const float e3 = k_f * cz2 * cz3;

        // ---- dot with W rows (coalesced float4) ----
        const float4 w0 = reinterpret_cast<const float4*>(W)[p];
        const float4 w1 = reinterpret_cast<const float4*>(W)[NPATCH + p];
        t0 += e0 * w0.x + e1 * w0.y + e2 * w0.z + e3 * w0.w;
        t1 += e0 * w1.x + e1 * w1.y + e2 * w1.z + e3 * w1.w;
    }

    // ---- block reduction: wave shuffle, then LDS across 16 waves ----
    #pragma unroll
    for (int off = 32; off > 0; off >>= 1) {
        t0 += __shfl_down(t0, off);
        t1 += __shfl_down(t1, off);
    }
    __shared__ float red0[BLK / 64], red1[BLK / 64];
    const int lane = threadIdx.x & 63;
    const int wv   = threadIdx.x >> 6;
    if (lane == 0) { red0[wv] = t0; red1[wv] = t1; }
    __syncthreads();
    if (threadIdx.x == 0) {
        float l0 = 0.f, l1 = 0.f;
        #pragma unroll
        for (int w = 0; w < BLK / 64; ++w) { l0 += red0[w]; l1 += red1[w]; }
        l0 += bias[0];
        l1 += bias[1];
        float m   = fmaxf(l0, l1);
        float lse = m + logf(__expf(l0 - m) + __expf(l1 - m));
        out[b * 2 + 0] = l0 - lse;
        out[b * 2 + 1] = l1 - lse;
    }
}

extern "C" void kernel_launch(void* const* d_in, const int* in_sizes, int n_in,
                              void* d_out, int out_size, void* d_ws, size_t ws_size,
                              hipStream_t stream) {
    const float* x    = (const float*)d_in[0];   // [64,100,100]
    const float* W    = (const float*)d_in[1];   // [2,10000]
    const float* bias = (const float*)d_in[2];   // [2]
    const float* qp   = (const float*)d_in[3];   // [6]
    float* out = (float*)d_out;                  // [64,2] fp32

    quanv_fused_kernel<<<NIMG, BLK, 0, stream>>>(x, W, bias, qp, out);
}